// Round 3
// baseline (135.252 us; speedup 1.0000x reference)
//
#include <hip/hip_runtime.h>

#define NPTS    6144
#define DIM     32
#define NB      2
#define NCELL   1000          // 10x10x10, cell edge = 0.03 = radius
#define R2      0.0009f
#define LEAFBIT 8192
#define PPT     6             // points per thread in build phase (6144/1024)
#define NBCAP   128           // max neighbors kept per point (obs ~13)
#define CHUNKS  128           // blocks per batch
#define SPB     (NPTS / CHUNKS)   // 48 original points per block
#define WPB     16            // waves per block (1024 threads)
#define SPW     (SPB / WPB)   // 3 points per wave

// ---- dynamic LDS layout (bytes, all 16B aligned) ----
#define SM_PTS    0                    // float4[6144]        98304
#define SM_CST    98304                // int[1001]            4004
#define SM_HIST   102400               // int[1024]            4096
#define SM_CUR    106496               // int[1024]            4096
#define SM_WSUM   110592               // int[16]                64
#define SM_LEAF   110656               // int                     4
#define SM_NB     110720               // int[16][128]         8192
#define SM_SV     118912               // int[16][128]         8192
#define SM_EI     127104               // float[16][32]        2048
#define SM_MEAN   129152               // float[16][32]        2048
#define SM_H      131200               // float[16][32]        2048
#define SMEM_BYTES 133248              // 130.1 KiB -> 1 block/CU

__device__ __forceinline__ int cellof(float x) {
    int c = (int)(x * (10.0f / 0.3f));
    return min(max(c, 0), 9);
}

// Single launch, zero d_ws traffic. Each block rebuilds the batch's
// cell-sorted candidate list in LDS (order inside a cell is nondeterministic
// but the SET per cell is identical across blocks). Work is partitioned by
// ORIGINAL point index (block k owns points [48k, 48k+48)), so every output
// row is written exactly once regardless of sort order.
__global__ __launch_bounds__(1024)
void fused(const float* __restrict__ points, const int* __restrict__ leaf,
           const float* __restrict__ emb,
           const float* __restrict__ W1, const float* __restrict__ b1,
           const float* __restrict__ W2, const float* __restrict__ b2,
           float* __restrict__ out)
{
    extern __shared__ char smem[];
    float4* s_pts   = (float4*)(smem + SM_PTS);
    int*    s_cst   = (int*)(smem + SM_CST);
    int*    s_hist  = (int*)(smem + SM_HIST);
    int*    s_cur   = (int*)(smem + SM_CUR);
    int*    s_wsum  = (int*)(smem + SM_WSUM);
    int*    s_leafp = (int*)(smem + SM_LEAF);
    int*    s_nb    = (int*)(smem + SM_NB);
    int*    s_sv    = (int*)(smem + SM_SV);
    float*  s_ei    = (float*)(smem + SM_EI);
    float*  s_mean  = (float*)(smem + SM_MEAN);
    float*  s_h     = (float*)(smem + SM_H);

    const int t     = threadIdx.x;
    const int b     = blockIdx.x / CHUNKS;
    const int chunk = blockIdx.x - b * CHUNKS;
    const int wid   = t >> 6, lane = t & 63;

    // ================= Phase 1: build cell-sorted points in LDS ============
    s_hist[t] = 0;
    if (t == 0) *s_leafp = 0;

    float px[PPT], py[PPT], pz[PPT];
    int   pc[PPT], pw[PPT];

    __syncthreads();

    int lc = 0;
    #pragma unroll
    for (int r = 0; r < PPT; ++r) {
        const int i  = r * 1024 + t;
        const int gi = b * NPTS + i;
        px[r] = points[gi * 3 + 0];
        py[r] = points[gi * 3 + 1];
        pz[r] = points[gi * 3 + 2];
        const int lf = leaf[gi] > 0 ? 1 : 0;
        lc += lf;
        pc[r] = (cellof(pz[r]) * 10 + cellof(py[r])) * 10 + cellof(px[r]);
        pw[r] = i + (lf ? LEAFBIT : 0);
        atomicAdd(&s_hist[pc[r]], 1);
    }
    #pragma unroll
    for (int off = 32; off > 0; off >>= 1) lc += __shfl_down(lc, off);
    if (lane == 0) atomicAdd(s_leafp, lc);
    __syncthreads();

    const int v = s_hist[t];
    int x = v;
    #pragma unroll
    for (int off = 1; off < 64; off <<= 1) {
        const int y = __shfl_up(x, off);
        if (lane >= off) x += y;
    }
    if (lane == 63) s_wsum[wid] = x;
    __syncthreads();
    if (t < 16) {
        int wv = s_wsum[t];
        #pragma unroll
        for (int off = 1; off < 16; off <<= 1) {
            const int y = __shfl_up(wv, off);
            if (t >= off) wv += y;
        }
        s_wsum[t] = wv;
    }
    __syncthreads();
    const int incl = x + (wid > 0 ? s_wsum[wid - 1] : 0);
    s_cur[t] = incl - v;
    if (t < NCELL) s_cst[t + 1] = incl;
    if (t == 0) s_cst[0] = 0;
    __syncthreads();

    #pragma unroll
    for (int r = 0; r < PPT; ++r) {
        const int pos = atomicAdd(&s_cur[pc[r]], 1);
        s_pts[pos] = make_float4(px[r], py[r], pz[r], (float)pw[r]);
    }
    __syncthreads();

    // ====== Phase 2: per-wave, partitioned by ORIGINAL index (no barriers) =
    const bool   ok   = *s_leafp >= 10;
    const float* embB = emb + (size_t)b * NPTS * DIM;
    float*       outB = out + (size_t)b * NPTS * DIM;
    const int    dd   = lane & 31;
    const int    half = lane >> 5;

    for (int rs = 0; rs < SPW; ++rs) {
        const int io = chunk * SPB + wid * SPW + rs;   // original index
        const int gi = b * NPTS + io;
        const float Px = points[gi * 3 + 0];
        const float Py = points[gi * 3 + 1];
        const float Pz = points[gi * 3 + 2];
        const bool  li = leaf[gi] > 0;

        const float4* e4   = (const float4*)(embB + (size_t)io * DIM);
        float4*       out4 = (float4*)(outB + (size_t)io * DIM);

        if (!(ok && li)) {                       // wave-uniform copy
            if (lane < DIM / 4) out4[lane] = e4[lane];
            continue;
        }

        // ---- center embedding + norm via shfl tree ----
        float ev = 0.0f;
        if (lane < DIM) { ev = ((const float*)e4)[lane]; s_ei[wid * DIM + lane] = ev; }
        float nsq = ev * ev;
        #pragma unroll
        for (int off = 16; off > 0; off >>= 1) nsq += __shfl_xor(nsq, off);
        const float ni2 = __shfl(nsq, 0);
        const float rni = 1.0f / fmaxf(sqrtf(ni2), 1e-8f);

        const int cx = cellof(Px), cy = cellof(Py), cz = cellof(Pz);

        int begv = 0, lenv = 0;
        if (lane < 9) {
            const int z = cz + lane / 3 - 1;
            const int y = cy + lane % 3 - 1;
            if ((unsigned)z <= 9u && (unsigned)y <= 9u) {
                const int rowb = (z * 10 + y) * 10;
                const int c0   = rowb + max(cx - 1, 0);
                const int c1   = rowb + min(cx + 1, 9);
                begv = s_cst[c0];
                lenv = s_cst[c1 + 1] - begv;
            }
        }
        const int rb0 = __shfl(begv, 0), rb1 = __shfl(begv, 1), rb2 = __shfl(begv, 2);
        const int rb3 = __shfl(begv, 3), rb4 = __shfl(begv, 4), rb5 = __shfl(begv, 5);
        const int rb6 = __shfl(begv, 6), rb7 = __shfl(begv, 7), rb8 = __shfl(begv, 8);
        const int ln0 = __shfl(lenv, 0), ln1 = __shfl(lenv, 1), ln2 = __shfl(lenv, 2);
        const int ln3 = __shfl(lenv, 3), ln4 = __shfl(lenv, 4), ln5 = __shfl(lenv, 5);
        const int ln6 = __shfl(lenv, 6), ln7 = __shfl(lenv, 7), ln8 = __shfl(lenv, 8);
        const int pf1 = ln0,       pf2 = pf1 + ln1, pf3 = pf2 + ln2;
        const int pf4 = pf3 + ln3, pf5 = pf4 + ln4, pf6 = pf5 + ln5;
        const int pf7 = pf6 + ln6, pf8 = pf7 + ln7, pf9 = pf8 + ln8;

        // ---- Phase A: scan candidates from LDS, compact hits ----
        int nbcnt = 0;
        for (int base = 0; base < pf9; base += 64) {
            const int g = base + lane;
            int j = 0;
            if (g < pf9) j = rb8 + g - pf8;
            if (g < pf8) j = rb7 + g - pf7;
            if (g < pf7) j = rb6 + g - pf6;
            if (g < pf6) j = rb5 + g - pf5;
            if (g < pf5) j = rb4 + g - pf4;
            if (g < pf4) j = rb3 + g - pf3;
            if (g < pf3) j = rb2 + g - pf2;
            if (g < pf2) j = rb1 + g - pf1;
            if (g < pf1) j = rb0 + g;
            const float4 Q  = s_pts[j];
            const float dx = Q.x - Px, dy = Q.y - Py, dz = Q.z - Pz;
            const float d2 = dx * dx + dy * dy + dz * dz;
            const int   jw = (int)Q.w;
            const bool  nb = (g < pf9) && (d2 < R2) && ((jw & LEAFBIT) != 0);
            const unsigned long long m = __ballot(nb);
            if (nb) {
                const int pos = nbcnt + __popcll(m & ((1ull << lane) - 1ull));
                if (pos < NBCAP) s_nb[wid * NBCAP + pos] = jw & (LEAFBIT - 1);
            }
            nbcnt += __popcll(m);
        }
        const int cnt_nb = nbcnt;

        // ---- Phase B: cosine, 2 lanes per hit; survivors -> s_sv ----
        int csim = 0;
        const int nh = min(cnt_nb, NBCAP);
        for (int h0 = 0; h0 < nh; h0 += 32) {
            const int h = h0 + dd;
            float dot = 0.0f, nj2 = 0.0f;
            int   jo  = 0;
            if (h < nh) {
                jo = s_nb[wid * NBCAP + h];
                const float4* ej4 = (const float4*)(embB + (size_t)jo * DIM) + half * 4;
                #pragma unroll
                for (int k = 0; k < 4; ++k) {
                    const float4 vq = ej4[k];
                    const float4 a  = *(const float4*)&s_ei[wid * DIM + 16 * half + 4 * k];
                    dot += a.x * vq.x + a.y * vq.y + a.z * vq.z + a.w * vq.w;
                    nj2 += vq.x * vq.x + vq.y * vq.y + vq.z * vq.z + vq.w * vq.w;
                }
            }
            dot += __shfl_xor(dot, 32);
            nj2 += __shfl_xor(nj2, 32);
            bool surv = false;
            if (h < nh && half == 0) {
                const float rnj = 1.0f / fmaxf(sqrtf(nj2), 1e-8f);
                surv = (dot * rni * rnj) > 0.7f;
            }
            const unsigned long long m = __ballot(surv);
            if (surv) {
                const int pos = csim + __popcll(m & ((1ull << lane) - 1ull));
                s_sv[wid * NBCAP + pos] = jo;
            }
            csim += __popcll(m);
        }

        if (!((cnt_nb > 1) && (csim > 0))) {     // wave-uniform copy
            if (lane < DIM) outB[(size_t)io * DIM + lane] = ev;
            continue;
        }

        // ---- survivor mean: rows split across lane halves ----
        float msum = 0.0f;
        for (int vv = half; vv < csim; vv += 2)
            msum += embB[(size_t)s_sv[wid * NBCAP + vv] * DIM + dd];
        msum += __shfl_xor(msum, 32);
        if (half == 0) s_mean[wid * DIM + dd] = msum / (float)csim;

        // ---- MLP layer 1: k-range split across halves ----
        float a = (half == 0) ? b1[dd] : 0.0f;
        #pragma unroll
        for (int k = 0; k < 16; ++k) {
            const int kk = half * 16 + k;
            a = fmaf(s_ei[wid * DIM + kk], W1[kk * DIM + dd], a);
        }
        #pragma unroll
        for (int k = 0; k < 16; ++k) {
            const int kk = half * 16 + k;
            a = fmaf(s_mean[wid * DIM + kk], W1[(DIM + kk) * DIM + dd], a);
        }
        a += __shfl_xor(a, 32);
        if (half == 0) s_h[wid * DIM + dd] = fmaxf(a, 0.0f);

        // ---- MLP layer 2 ----
        float c = (half == 0) ? b2[dd] : 0.0f;
        #pragma unroll
        for (int k = 0; k < 16; ++k) {
            const int kk = half * 16 + k;
            c = fmaf(s_h[wid * DIM + kk], W2[kk * DIM + dd], c);
        }
        c += __shfl_xor(c, 32);
        if (half == 0)
            outB[(size_t)io * DIM + dd] = c;
    }
}

extern "C" void kernel_launch(void* const* d_in, const int* in_sizes, int n_in,
                              void* d_out, int out_size, void* d_ws, size_t ws_size,
                              hipStream_t stream) {
    (void)d_ws; (void)ws_size; (void)in_sizes; (void)n_in; (void)out_size;
    const float* points = (const float*)d_in[0];
    const float* emb    = (const float*)d_in[1];
    const int*   leaf   = (const int*)d_in[2];
    const float* W1     = (const float*)d_in[3];
    const float* b1     = (const float*)d_in[4];
    const float* W2     = (const float*)d_in[5];
    const float* b2     = (const float*)d_in[6];
    float*       outp   = (float*)d_out;

    static bool attr_set = false;
    if (!attr_set) {
        (void)hipFuncSetAttribute(reinterpret_cast<const void*>(&fused),
                                  hipFuncAttributeMaxDynamicSharedMemorySize,
                                  SMEM_BYTES);
        attr_set = true;
    }

    fused<<<NB * CHUNKS, 1024, SMEM_BYTES, stream>>>(points, leaf, emb,
                                                     W1, b1, W2, b2, outp);
}

// Round 4
// 91.741 us; speedup vs baseline: 1.4743x; 1.4743x over previous
//
#include <hip/hip_runtime.h>

#define NPTS    6144
#define DIM     32
#define NB      2
#define NCELL   1000          // 10x10x10, cell edge = 0.03 = radius
#define R2      0.0009f
#define NWAVES  4
#define BLOCK   (NWAVES * 64)
#define LEAFBIT 8192
#define PPT     6             // points per thread in build_cells (6144/1024)
#define NBCAP   128           // max neighbors kept per point (obs ~13)
#define COPYBLK 64            // extra blocks in K1: copy emb->out + warm L3

__device__ __forceinline__ int cellof(float x) {
    int c = (int)(x * (10.0f / 0.3f));
    return min(max(c, 0), 9);
}

// ---- ws layout (ints) ----
#define WS_LEAF   0
#define WS_CSTART 4
#define WS_SORTED 2008   // float4 [NB][NPTS], byte 8032 (16B aligned)

// K1: blocks 0..NB-1: per-batch LDS histogram -> shfl scan -> cursor scatter
// (shared ONCE via ws — R3 showed per-block rebuild thrashes L2, 61MB fetch).
// Blocks NB..: (a) warm-read points+leaf so the build blocks' first-touch
// misses (L3 was just flushed by the 256MB ws poison fill) become L3 hits,
// (b) bulk float4 copy emb->out so refine never writes non-refined rows.
__global__ __launch_bounds__(1024)
void build_cells(const float* __restrict__ points, const int* __restrict__ leaf,
                 const float* __restrict__ emb, float* __restrict__ out,
                 int* __restrict__ ws)
{
    __shared__ int s_hist[1024];
    __shared__ int s_cursor[1024];
    __shared__ int s_wsum[16];
    __shared__ int s_leaf;

    if (blockIdx.x >= NB) {                    // ---- warm + copy blocks ----
        const int cb = blockIdx.x - NB;
        // (a) warm points+leaf into L3 (keeps build blocks off HBM latency)
        float accf = 0.0f;
        const int totalp = NB * NPTS * 3;
        for (int i = cb * 1024 + threadIdx.x; i < totalp; i += COPYBLK * 1024)
            accf += points[i];
        int acci = 0;
        const int totall = NB * NPTS;
        for (int i = cb * 1024 + threadIdx.x; i < totall; i += COPYBLK * 1024)
            acci += leaf[i];
        asm volatile("" :: "v"(accf), "v"(acci));   // keep loads live (rule #17)
        // (b) pre-fill out with emb
        const float4* src = (const float4*)emb;
        float4*       dst = (float4*)out;
        const int total4 = NB * NPTS * (DIM / 4);          // 98304
        for (int i = cb * 1024 + threadIdx.x; i < total4; i += COPYBLK * 1024)
            dst[i] = src[i];
        return;
    }

    const int t = threadIdx.x;
    const int b = blockIdx.x;
    const int w = t >> 6, lane = t & 63;

    s_hist[t] = 0;
    if (t == 0) s_leaf = 0;

    float px[PPT], py[PPT], pz[PPT];
    int   pc[PPT], pw[PPT];

    __syncthreads();

    int lc = 0;
    #pragma unroll
    for (int r = 0; r < PPT; ++r) {
        const int i  = r * 1024 + t;
        const int gi = b * NPTS + i;
        px[r] = points[gi * 3 + 0];
        py[r] = points[gi * 3 + 1];
        pz[r] = points[gi * 3 + 2];
        const int lf = leaf[gi] > 0 ? 1 : 0;
        lc += lf;
        pc[r] = (cellof(pz[r]) * 10 + cellof(py[r])) * 10 + cellof(px[r]);
        pw[r] = i + (lf ? LEAFBIT : 0);
        atomicAdd(&s_hist[pc[r]], 1);
    }
    #pragma unroll
    for (int off = 32; off > 0; off >>= 1) lc += __shfl_down(lc, off);
    if (lane == 0) atomicAdd(&s_leaf, lc);
    __syncthreads();

    const int v = s_hist[t];
    int x = v;
    #pragma unroll
    for (int off = 1; off < 64; off <<= 1) {
        const int y = __shfl_up(x, off);
        if (lane >= off) x += y;
    }
    if (lane == 63) s_wsum[w] = x;
    __syncthreads();
    if (t < 16) {
        int wv = s_wsum[t];
        #pragma unroll
        for (int off = 1; off < 16; off <<= 1) {
            const int y = __shfl_up(wv, off);
            if (t >= off) wv += y;
        }
        s_wsum[t] = wv;
    }
    __syncthreads();
    const int incl = x + (w > 0 ? s_wsum[w - 1] : 0);
    s_cursor[t] = incl - v;

    if (t < NCELL) ws[WS_CSTART + b * (NCELL + 1) + t + 1] = incl;
    if (t == 0) {
        ws[WS_CSTART + b * (NCELL + 1)] = 0;
        ws[WS_LEAF + b] = s_leaf;
    }
    __syncthreads();

    float4* sorted = (float4*)(ws + WS_SORTED) + (size_t)b * NPTS;
    #pragma unroll
    for (int r = 0; r < PPT; ++r) {
        const int pos = atomicAdd(&s_cursor[pc[r]], 1);
        sorted[pos] = make_float4(px[r], py[r], pz[r], (float)pw[r]);
    }
}

// K2: wave per point; out pre-filled with emb, so non-refined waves write
// nothing. Phase B accumulates surviving rows IN REGISTERS (they're already
// loaded for the cosine test) -> no s_sv, no serial global-gather mean loop;
// final mean via 5-level shfl_xor tree within each 32-lane dim-half group.
__global__ __launch_bounds__(BLOCK, 4)
void refine(const float* __restrict__ emb,
            const float* __restrict__ W1, const float* __restrict__ b1,
            const float* __restrict__ W2, const float* __restrict__ b2,
            const int* __restrict__ ws, float* __restrict__ out)
{
    __shared__ __align__(16) float s_ei[NWAVES][DIM];
    __shared__ __align__(16) float s_mean[NWAVES][DIM];
    __shared__ float s_h[NWAVES][DIM];
    __shared__ int   s_nb[NWAVES][NBCAP];

    const int tid  = threadIdx.x;
    const int wid  = tid >> 6;
    const int lane = tid & 63;
    const int s    = blockIdx.x * NWAVES + wid;
    const int b    = s / NPTS;
    const int slot = s - b * NPTS;

    if (ws[WS_LEAF + b] < 10) return;            // batch-uniform: out = emb done

    const float4* srt  = (const float4*)(ws + WS_SORTED) + (size_t)b * NPTS;
    const int*    cst  = ws + WS_CSTART + b * (NCELL + 1);
    const float*  embB = emb + (size_t)b * NPTS * DIM;

    const float4 P  = srt[slot];
    const int    iw = (int)P.w;
    if (!(iw & LEAFBIT)) return;                 // non-leaf: out = emb done
    const int io = iw & (LEAFBIT - 1);

    // ---- load center embedding, norm via shfl tree ----
    const float* ei = embB + (size_t)io * DIM;
    float ev = 0.0f;
    if (lane < DIM) { ev = ei[lane]; s_ei[wid][lane] = ev; }
    float nsq = ev * ev;
    #pragma unroll
    for (int off = 16; off > 0; off >>= 1) nsq += __shfl_xor(nsq, off);
    const float ni2 = __shfl(nsq, 0);
    const float rni = 1.0f / fmaxf(sqrtf(ni2), 1e-8f);

    const int cx = cellof(P.x), cy = cellof(P.y), cz = cellof(P.z);

    int begv = 0, lenv = 0;
    if (lane < 9) {
        const int z = cz + lane / 3 - 1;
        const int y = cy + lane % 3 - 1;
        if ((unsigned)z <= 9u && (unsigned)y <= 9u) {
            const int rowb = (z * 10 + y) * 10;
            const int c0   = rowb + max(cx - 1, 0);
            const int c1   = rowb + min(cx + 1, 9);
            begv = cst[c0];
            lenv = cst[c1 + 1] - begv;
        }
    }
    const int rb0 = __shfl(begv, 0), rb1 = __shfl(begv, 1), rb2 = __shfl(begv, 2);
    const int rb3 = __shfl(begv, 3), rb4 = __shfl(begv, 4), rb5 = __shfl(begv, 5);
    const int rb6 = __shfl(begv, 6), rb7 = __shfl(begv, 7), rb8 = __shfl(begv, 8);
    const int ln0 = __shfl(lenv, 0), ln1 = __shfl(lenv, 1), ln2 = __shfl(lenv, 2);
    const int ln3 = __shfl(lenv, 3), ln4 = __shfl(lenv, 4), ln5 = __shfl(lenv, 5);
    const int ln6 = __shfl(lenv, 6), ln7 = __shfl(lenv, 7), ln8 = __shfl(lenv, 8);
    const int pf1 = ln0,       pf2 = pf1 + ln1, pf3 = pf2 + ln2;
    const int pf4 = pf3 + ln3, pf5 = pf4 + ln4, pf6 = pf5 + ln5;
    const int pf7 = pf6 + ln6, pf8 = pf7 + ln7, pf9 = pf8 + ln8;

    // ---- Phase A: scan candidates, compact nb hits into s_nb ----
    int nbcnt = 0;
    for (int base = 0; base < pf9; base += 64) {
        const int g = base + lane;
        int j = 0;
        if (g < pf9) j = rb8 + g - pf8;
        if (g < pf8) j = rb7 + g - pf7;
        if (g < pf7) j = rb6 + g - pf6;
        if (g < pf6) j = rb5 + g - pf5;
        if (g < pf5) j = rb4 + g - pf4;
        if (g < pf4) j = rb3 + g - pf3;
        if (g < pf3) j = rb2 + g - pf2;
        if (g < pf2) j = rb1 + g - pf1;
        if (g < pf1) j = rb0 + g;
        const float4 Q  = srt[j];
        const float dx = Q.x - P.x, dy = Q.y - P.y, dz = Q.z - P.z;
        const float d2 = dx * dx + dy * dy + dz * dz;
        const int   jw = (int)Q.w;
        const bool  nb = (g < pf9) && (d2 < R2) && ((jw & LEAFBIT) != 0);
        const unsigned long long m = __ballot(nb);
        if (nb) {
            const int pos = nbcnt + __popcll(m & ((1ull << lane) - 1ull));
            if (pos < NBCAP) s_nb[wid][pos] = jw & (LEAFBIT - 1);
        }
        nbcnt += __popcll(m);
    }
    const int cnt_nb = nbcnt;

    // ---- Phase B: cosine, 2 lanes/hit; survivors accumulate in registers ---
    const int dd   = lane & 31;
    const int half = lane >> 5;
    float4 m0 = {0.f,0.f,0.f,0.f}, m1 = {0.f,0.f,0.f,0.f};
    float4 m2 = {0.f,0.f,0.f,0.f}, m3 = {0.f,0.f,0.f,0.f};
    int csim = 0;
    const int nh = min(cnt_nb, NBCAP);
    for (int h0 = 0; h0 < nh; h0 += 32) {
        const int h = h0 + dd;
        float dot = 0.0f, nj2 = 0.0f;
        float4 v0 = {0.f,0.f,0.f,0.f}, v1 = {0.f,0.f,0.f,0.f};
        float4 v2 = {0.f,0.f,0.f,0.f}, v3 = {0.f,0.f,0.f,0.f};
        if (h < nh) {
            const int jo = s_nb[wid][h];
            const float4* ej4 = (const float4*)(embB + (size_t)jo * DIM) + half * 4;
            v0 = ej4[0]; v1 = ej4[1]; v2 = ej4[2]; v3 = ej4[3];
            const float4 a0 = *(const float4*)&s_ei[wid][16 * half + 0];
            const float4 a1 = *(const float4*)&s_ei[wid][16 * half + 4];
            const float4 a2 = *(const float4*)&s_ei[wid][16 * half + 8];
            const float4 a3 = *(const float4*)&s_ei[wid][16 * half + 12];
            dot = a0.x*v0.x + a0.y*v0.y + a0.z*v0.z + a0.w*v0.w
                + a1.x*v1.x + a1.y*v1.y + a1.z*v1.z + a1.w*v1.w
                + a2.x*v2.x + a2.y*v2.y + a2.z*v2.z + a2.w*v2.w
                + a3.x*v3.x + a3.y*v3.y + a3.z*v3.z + a3.w*v3.w;
            nj2 = v0.x*v0.x + v0.y*v0.y + v0.z*v0.z + v0.w*v0.w
                + v1.x*v1.x + v1.y*v1.y + v1.z*v1.z + v1.w*v1.w
                + v2.x*v2.x + v2.y*v2.y + v2.z*v2.z + v2.w*v2.w
                + v3.x*v3.x + v3.y*v3.y + v3.z*v3.z + v3.w*v3.w;
        }
        dot += __shfl_xor(dot, 32);
        nj2 += __shfl_xor(nj2, 32);
        bool surv = false;
        if (h < nh) {                            // both halves decide identically
            const float rnj = 1.0f / fmaxf(sqrtf(nj2), 1e-8f);
            surv = (dot * rni * rnj) > 0.7f;
        }
        if (surv) {
            m0.x += v0.x; m0.y += v0.y; m0.z += v0.z; m0.w += v0.w;
            m1.x += v1.x; m1.y += v1.y; m1.z += v1.z; m1.w += v1.w;
            m2.x += v2.x; m2.y += v2.y; m2.z += v2.z; m2.w += v2.w;
            m3.x += v3.x; m3.y += v3.y; m3.z += v3.z; m3.w += v3.w;
        }
        const unsigned long long mm = __ballot(surv);
        csim += __popcll(mm & 0xffffffffull);    // lower half = one bit per hit
    }

    if (!((cnt_nb > 1) && (csim > 0))) return;   // out = emb done (wave-uniform)

    // ---- reduce mean partials across the 32-lane group (same dim-half) ----
    #pragma unroll
    for (int off = 1; off < 32; off <<= 1) {
        m0.x += __shfl_xor(m0.x, off); m0.y += __shfl_xor(m0.y, off);
        m0.z += __shfl_xor(m0.z, off); m0.w += __shfl_xor(m0.w, off);
        m1.x += __shfl_xor(m1.x, off); m1.y += __shfl_xor(m1.y, off);
        m1.z += __shfl_xor(m1.z, off); m1.w += __shfl_xor(m1.w, off);
        m2.x += __shfl_xor(m2.x, off); m2.y += __shfl_xor(m2.y, off);
        m2.z += __shfl_xor(m2.z, off); m2.w += __shfl_xor(m2.w, off);
        m3.x += __shfl_xor(m3.x, off); m3.y += __shfl_xor(m3.y, off);
        m3.z += __shfl_xor(m3.z, off); m3.w += __shfl_xor(m3.w, off);
    }
    if (dd == 0) {
        const float inv = 1.0f / (float)csim;
        float4* mp = (float4*)&s_mean[wid][16 * half];
        mp[0] = make_float4(m0.x*inv, m0.y*inv, m0.z*inv, m0.w*inv);
        mp[1] = make_float4(m1.x*inv, m1.y*inv, m1.z*inv, m1.w*inv);
        mp[2] = make_float4(m2.x*inv, m2.y*inv, m2.z*inv, m2.w*inv);
        mp[3] = make_float4(m3.x*inv, m3.y*inv, m3.z*inv, m3.w*inv);
    }

    // ---- MLP layer 1: k-range split across halves, shfl combine ----
    float a = (half == 0) ? b1[dd] : 0.0f;
    #pragma unroll
    for (int k = 0; k < 16; ++k) {
        const int kk = half * 16 + k;
        a = fmaf(s_ei[wid][kk], W1[kk * DIM + dd], a);
    }
    #pragma unroll
    for (int k = 0; k < 16; ++k) {
        const int kk = half * 16 + k;
        a = fmaf(s_mean[wid][kk], W1[(DIM + kk) * DIM + dd], a);
    }
    a += __shfl_xor(a, 32);
    if (half == 0) s_h[wid][dd] = fmaxf(a, 0.0f);

    // ---- MLP layer 2 ----
    float c = (half == 0) ? b2[dd] : 0.0f;
    #pragma unroll
    for (int k = 0; k < 16; ++k) {
        const int kk = half * 16 + k;
        c = fmaf(s_h[wid][kk], W2[kk * DIM + dd], c);
    }
    c += __shfl_xor(c, 32);
    if (half == 0)
        out[((size_t)b * NPTS + io) * DIM + dd] = c;
}

extern "C" void kernel_launch(void* const* d_in, const int* in_sizes, int n_in,
                              void* d_out, int out_size, void* d_ws, size_t ws_size,
                              hipStream_t stream) {
    (void)in_sizes; (void)n_in; (void)out_size; (void)ws_size;
    const float* points = (const float*)d_in[0];
    const float* emb    = (const float*)d_in[1];
    const int*   leaf   = (const int*)d_in[2];
    const float* W1     = (const float*)d_in[3];
    const float* b1     = (const float*)d_in[4];
    const float* W2     = (const float*)d_in[5];
    const float* b2     = (const float*)d_in[6];
    float*       outp   = (float*)d_out;
    int*         ws     = (int*)d_ws;

    build_cells<<<NB + COPYBLK, 1024, 0, stream>>>(points, leaf, emb, outp, ws);

    const int grid = (NB * NPTS) / NWAVES;                       // 3072
    refine<<<grid, BLOCK, 0, stream>>>(emb, W1, b1, W2, b2, ws, outp);
}